// Round 3
// baseline (660.403 us; speedup 1.0000x reference)
//
#include <hip/hip_runtime.h>
#include <hip/hip_bf16.h>
#include <math.h>

// Problem constants (fixed by setup_inputs)
#define BB 16
#define CC 192
#define TS 2048
#define TT 512
#define KK 384   // 2*CC

// d_out float offsets
#define OFF_PATH 0
#define OFF_DUR  (16777216)
#define OFF_LOGW (OFF_DUR + 8192)
#define OFF_MEXP (OFF_LOGW + 8192)
#define OFF_LEXP (OFF_MEXP + 6291456)
#define OFF_TMASK (OFF_LEXP + 6291456)
#define OFF_SMASK (OFF_TMASK + 8192)

#define NEGC (-1e9)

// ---------------------------------------------------------------------------
// prep: per (b,u): s = exp(-2 logs), Bmat rows {m*s, s}, avec = nc1+nc4,
// plus text_mask / spec_mask outputs.
__global__ __launch_bounds__(512) void vits_prep(
    const float* __restrict__ m_p, const float* __restrict__ logs_p,
    const int* __restrict__ spec_len, const int* __restrict__ text_len,
    float* __restrict__ Bmat, float* __restrict__ avec,
    float* __restrict__ tmask, float* __restrict__ smask)
{
    const int b = blockIdx.x;
    const int u = threadIdx.x;
    const float C0 = -0.91893853320467274178f; // -0.5*log(2*pi)
    float a_acc = 0.f;
    for (int c = 0; c < CC; ++c) {
        float lg = logs_p[((size_t)b*CC + c)*TT + u];
        float mm = m_p[((size_t)b*CC + c)*TT + u];
        float s  = expf(-2.f*lg);
        float ms = mm * s;
        Bmat[((size_t)b*KK + 2*c    )*TT + u] = ms;  // pairs with z      -> neg_cent3
        Bmat[((size_t)b*KK + 2*c + 1)*TT + u] = s;   // pairs with -.5z^2 -> neg_cent2
        a_acc += C0 - lg - 0.5f*mm*ms;               // nc1 + nc4 terms
    }
    avec[b*TT + u] = a_acc;
    tmask[b*TT + u] = (u < text_len[b]) ? 1.f : 0.f;
    for (int t = u; t < TS; t += TT)
        smask[b*TS + t] = (t < spec_len[b]) ? 1.f : 0.f;
}

// ---------------------------------------------------------------------------
// gemm: nc[b][t][u] = avec[b][u] + sum_k X[k][t] * Bmat[k][u]
// X[2c][t] = z[b][c][t], X[2c+1][t] = -0.5*z^2. 64x64 tile, 4x4 microtile.
__global__ __launch_bounds__(256) void vits_gemm(
    const float* __restrict__ z, const float* __restrict__ Bmat,
    const float* __restrict__ avec, float* __restrict__ out)
{
    const int b  = blockIdx.z;
    const int t0 = blockIdx.y * 64;
    const int u0 = blockIdx.x * 64;
    __shared__ float As[16][68];
    __shared__ float Bs[16][68];
    const int tid = threadIdx.x;
    const int tx = tid & 15, ty = tid >> 4;
    float acc[4][4] = {};
    const float* zb = z    + (size_t)b * CC * TS;
    const float* Bb = Bmat + (size_t)b * KK * TT;
    for (int kc = 0; kc < KK/16; ++kc) {
        {
            int c_l = tid >> 5;            // 0..7
            int t_l = (tid & 31) * 2;
            const float* zp = zb + (size_t)(kc*8 + c_l)*TS + t0 + t_l;
            float2 zv = *(const float2*)zp;
            float2 z1 = make_float2(zv.x, zv.y);
            float2 z2 = make_float2(-0.5f*zv.x*zv.x, -0.5f*zv.y*zv.y);
            *(float2*)&As[2*c_l  ][t_l] = z1;
            *(float2*)&As[2*c_l+1][t_l] = z2;
            int k_l = tid >> 4;            // 0..15
            int u_l = (tid & 15) * 4;
            const float* bp = Bb + (size_t)(kc*16 + k_l)*TT + u0 + u_l;
            *(float4*)&Bs[k_l][u_l] = *(const float4*)bp;
        }
        __syncthreads();
        #pragma unroll
        for (int kk = 0; kk < 16; ++kk) {
            float4 av = *(const float4*)&As[kk][ty*4];
            float4 bv = *(const float4*)&Bs[kk][tx*4];
            float aa[4] = {av.x, av.y, av.z, av.w};
            float bb[4] = {bv.x, bv.y, bv.z, bv.w};
            #pragma unroll
            for (int i = 0; i < 4; ++i)
                #pragma unroll
                for (int jj = 0; jj < 4; ++jj)
                    acc[i][jj] += aa[i]*bb[jj];
        }
        __syncthreads();
    }
    float4 a4 = *(const float4*)(avec + b*TT + u0 + tx*4);
    float ab[4] = {a4.x, a4.y, a4.z, a4.w};
    #pragma unroll
    for (int i = 0; i < 4; ++i) {
        float4 o;
        o.x = acc[i][0] + ab[0];
        o.y = acc[i][1] + ab[1];
        o.z = acc[i][2] + ab[2];
        o.w = acc[i][3] + ab[3];
        *(float4*)(out + ((size_t)b*TS + t0 + ty*4 + i)*TT + u0 + tx*4) = o;
    }
}

// ---------------------------------------------------------------------------
// dp: forward Viterbi (f64), producer-consumer: wave0 computes, waves 1-3
// stage nc rows into a double-buffered LDS ring (CH rows/chunk), one
// __syncthreads per chunk. dirs bit-packed per j along t, bank-swizzled.
#define CH 6
// dirs[j][w] with bank swizzle: lanes (j>>3) spread across banks
#define DIRS(j,w) dirs[((j)<<6) | ((w) ^ (((j)>>3)&31))]

__global__ __launch_bounds__(256, 1) void vits_dp(
    const float* __restrict__ nc,
    const int* __restrict__ spec_len, const int* __restrict__ text_len,
    float* __restrict__ dur, float* __restrict__ logw, int* __restrict__ jt)
{
    __shared__ unsigned int dirs[TT*(TS/32)];   // 512*64 u32 = 128 KB (swizzled)
    __shared__ float4 ring4[2][CH][128];        // 24 KB: [slot l]=floats[8l..8l+3], [64+l]=[8l+4..8l+7]
    __shared__ int Tr[TT + 1];

    const int tid  = threadIdx.x;
    const int lane = tid & 63;
    const int wid  = tid >> 6;
    const int b = blockIdx.x;
    const int SL = spec_len[b], TL = text_len[b];
    const int nch = (SL + CH - 1) / CH;

    const float* ncb = nc + (size_t)b*TS*TT;

    double q[8];
    #pragma unroll
    for (int e = 0; e < 8; ++e) q[e] = NEGC;
    if (tid == 0) q[0] = 0.0;
    unsigned int bits[8] = {0,0,0,0,0,0,0,0};

    for (int c = 0; c <= nch; ++c) {
        if (wid != 0) {
            if (c < nch) {
                const int p = wid - 1;
                #pragma unroll
                for (int rr = 0; rr < 2; ++rr) {
                    int r = p + rr*3;
                    int t = c*CH + r;
                    int tc = (t < SL) ? t : (SL - 1);
                    const float* rowp = ncb + (size_t)tc*TT + (lane << 3);
                    float4 va = *(const float4*)(rowp);
                    float4 vb = *(const float4*)(rowp + 4);
                    ring4[c & 1][r][lane]      = va;
                    ring4[c & 1][r][64 + lane] = vb;
                }
            }
        } else if (c > 0) {
            const int cc = c - 1;
            const int par = cc & 1;
            float4 F0[CH], F1[CH];
            #pragma unroll
            for (int r = 0; r < CH; ++r) {
                F0[r] = ring4[par][r][lane];
                F1[r] = ring4[par][r][64 + lane];
            }
            #pragma unroll
            for (int r = 0; r < CH; ++r) {
                int t = cc*CH + r;
                if (t >= SL) break;
                double up = __shfl_up(q[7], 1);
                if (lane == 0) up = NEGC;
                float f[8] = {F0[r].x, F0[r].y, F0[r].z, F0[r].w,
                              F1[r].x, F1[r].y, F1[r].z, F1[r].w};
                #pragma unroll
                for (int e = 7; e >= 1; --e) {
                    bool d = (q[e-1] >= q[e]);          // ref: q_shift >= q
                    bits[e] = (bits[e] << 1) | (unsigned)d;
                    q[e] = (double)f[e] + fmax(q[e-1], q[e]);
                }
                {
                    bool d = (up >= q[0]);
                    bits[0] = (bits[0] << 1) | (unsigned)d;
                    q[0] = (double)f[0] + fmax(up, q[0]);
                }
                if ((t & 31) == 31) {
                    int w = t >> 5;
                    #pragma unroll
                    for (int e = 0; e < 8; ++e) { DIRS(lane*8+e, w) = bits[e]; bits[e] = 0; }
                }
            }
        }
        __syncthreads();
    }

    if (wid == 0 && (SL & 31)) {
        int w = SL >> 5, r = SL & 31;
        #pragma unroll
        for (int e = 0; e < 8; ++e) DIRS(lane*8+e, w) = bits[e] << (32 - r);
    }
    __syncthreads();

    for (int i = tid; i <= TT; i += 256) Tr[i] = 0;
    __syncthreads();

    if (tid == 0) {
        Tr[TL] = SL;
        int j = TL - 1, tc = SL - 1;
        // Tr[j] = first frame aligned to text index j (transition time)
        while (j > 0 && tc >= 0) {
            int w = tc >> 5;
            int bcur = 31 - (tc & 31);
            unsigned int W = DIRS(j, w) & (0xFFFFFFFFu << bcur);
            if (W) {
                int bp = __ffs(W) - 1;          // lowest set bit >= bcur
                int tp = (w << 5) + 31 - bp;    // = largest t' <= tc with d=1
                Tr[j] = tp;
                --j;
                tc = tp - 1;
            } else {
                if (w == 0) break;
                tc = (w << 5) - 1;
            }
        }
    }
    __syncthreads();

    for (int u = tid; u < TT; u += 256) {
        float dv = (u < TL) ? (float)(Tr[u+1] - Tr[u]) : 0.0f;
        dur[b*TT + u] = dv;
        logw[b*TT + u] = (u < TL) ? logf(dv + 1e-6f) : 0.0f;
    }
    // jt: range-fill [Tr[u], Tr[u+1]) -> u
    for (int u = 0; u < TL; ++u) {
        int t1 = Tr[u+1];
        for (int t = Tr[u] + tid; t < t1; t += 256) jt[b*TS + t] = u;
    }
    for (int t = SL + tid; t < TS; t += 256) jt[b*TS + t] = -1;
}

// ---------------------------------------------------------------------------
// path: path[b][t][u] = (u == jt[b][t]) ? 1 : 0   (float4-vectorized)
__global__ void vits_path(const int* __restrict__ jt, float4* __restrict__ path)
{
    int idx = blockIdx.x*blockDim.x + threadIdx.x;
    const int total = BB*TS*(TT/4);
    for (; idx < total; idx += gridDim.x*blockDim.x) {
        int u4 = idx & (TT/4 - 1);
        int bt = idx >> 7;
        int j = jt[bt];
        float4 v = make_float4(0.f,0.f,0.f,0.f);
        int r = j - (u4 << 2);
        if (r >= 0 && r < 4) ((float*)&v)[r] = 1.f;
        path[idx] = v;
    }
}

// ---------------------------------------------------------------------------
// m/logs expansion: out[b][c][t] = (jt>=0) ? src[b][c][jt] : 0
__global__ void vits_mlexp(const int* __restrict__ jt,
    const float* __restrict__ m_p, const float* __restrict__ logs_p,
    float4* __restrict__ mexp, float4* __restrict__ lexp)
{
    int idx = blockIdx.x*blockDim.x + threadIdx.x;
    const int total = BB*CC*(TS/4);
    for (; idx < total; idx += gridDim.x*blockDim.x) {
        int t4 = idx & (TS/4 - 1);
        int bc = idx >> 9;
        int b = bc / CC;
        int4 jv = *(const int4*)(jt + b*TS + (t4 << 2));
        const float* mrow = m_p    + (size_t)bc*TT;
        const float* lrow = logs_p + (size_t)bc*TT;
        float4 mv, lv;
        mv.x = (jv.x >= 0) ? mrow[jv.x] : 0.f;  lv.x = (jv.x >= 0) ? lrow[jv.x] : 0.f;
        mv.y = (jv.y >= 0) ? mrow[jv.y] : 0.f;  lv.y = (jv.y >= 0) ? lrow[jv.y] : 0.f;
        mv.z = (jv.z >= 0) ? mrow[jv.z] : 0.f;  lv.z = (jv.z >= 0) ? lrow[jv.z] : 0.f;
        mv.w = (jv.w >= 0) ? mrow[jv.w] : 0.f;  lv.w = (jv.w >= 0) ? lrow[jv.w] : 0.f;
        mexp[idx] = mv;
        lexp[idx] = lv;
    }
}

// ---------------------------------------------------------------------------
extern "C" void kernel_launch(void* const* d_in, const int* in_sizes, int n_in,
                              void* d_out, int out_size, void* d_ws, size_t ws_size,
                              hipStream_t stream) {
    const float* z_p      = (const float*)d_in[0];
    const float* m_p      = (const float*)d_in[1];
    const float* logs_p   = (const float*)d_in[2];
    const int*   spec_len = (const int*)d_in[3];
    const int*   text_len = (const int*)d_in[4];
    float* out = (float*)d_out;

    float* Bmat = (float*)d_ws;                  // [B][384][512] f32 = 12.6 MB
    float* avec = Bmat + (size_t)BB*KK*TT;       // [B][512]
    int*   jt   = (int*)(avec + BB*TT);          // [B][2048]

    float* path  = out + OFF_PATH;   // doubles as neg_cent staging
    float* dur   = out + OFF_DUR;
    float* logw  = out + OFF_LOGW;
    float* mexp  = out + OFF_MEXP;
    float* lexp  = out + OFF_LEXP;
    float* tmask = out + OFF_TMASK;
    float* smask = out + OFF_SMASK;

    vits_prep<<<BB, 512, 0, stream>>>(m_p, logs_p, spec_len, text_len,
                                      Bmat, avec, tmask, smask);
    vits_gemm<<<dim3(TT/64, TS/64, BB), 256, 0, stream>>>(z_p, Bmat, avec, path);
    vits_dp<<<BB, 256, 0, stream>>>(path, spec_len, text_len, dur, logw, jt);
    vits_path<<<2048, 256, 0, stream>>>(jt, (float4*)path);
    vits_mlexp<<<2048, 256, 0, stream>>>(jt, m_p, logs_p, (float4*)mexp, (float4*)lexp);
}

// Round 4
// 558.793 us; speedup vs baseline: 1.1818x; 1.1818x over previous
//
#include <hip/hip_runtime.h>
#include <hip/hip_bf16.h>
#include <math.h>

// Problem constants (fixed by setup_inputs)
#define BB 16
#define CC 192
#define TS 2048
#define TT 512
#define KK 384   // 2*CC

// d_out float offsets
#define OFF_PATH 0
#define OFF_DUR  (16777216)
#define OFF_LOGW (OFF_DUR + 8192)
#define OFF_MEXP (OFF_LOGW + 8192)
#define OFF_LEXP (OFF_MEXP + 6291456)
#define OFF_TMASK (OFF_LEXP + 6291456)
#define OFF_SMASK (OFF_TMASK + 8192)

#define NEGC (-1e9)

// ---------------------------------------------------------------------------
// prep: per (b,u): s = exp(-2 logs), Bmat rows {m*s, s}, avec = nc1+nc4,
// plus text_mask / spec_mask outputs.
__global__ __launch_bounds__(512) void vits_prep(
    const float* __restrict__ m_p, const float* __restrict__ logs_p,
    const int* __restrict__ spec_len, const int* __restrict__ text_len,
    float* __restrict__ Bmat, float* __restrict__ avec,
    float* __restrict__ tmask, float* __restrict__ smask)
{
    const int b = blockIdx.x;
    const int u = threadIdx.x;
    const float C0 = -0.91893853320467274178f; // -0.5*log(2*pi)
    float a_acc = 0.f;
    for (int c = 0; c < CC; ++c) {
        float lg = logs_p[((size_t)b*CC + c)*TT + u];
        float mm = m_p[((size_t)b*CC + c)*TT + u];
        float s  = expf(-2.f*lg);
        float ms = mm * s;
        Bmat[((size_t)b*KK + 2*c    )*TT + u] = ms;  // pairs with z      -> neg_cent3
        Bmat[((size_t)b*KK + 2*c + 1)*TT + u] = s;   // pairs with -.5z^2 -> neg_cent2
        a_acc += C0 - lg - 0.5f*mm*ms;               // nc1 + nc4 terms
    }
    avec[b*TT + u] = a_acc;
    tmask[b*TT + u] = (u < text_len[b]) ? 1.f : 0.f;
    for (int t = u; t < TS; t += TT)
        smask[b*TS + t] = (t < spec_len[b]) ? 1.f : 0.f;
}

// ---------------------------------------------------------------------------
// gemm: nc[b][t][u] = avec[b][u] + sum_k X[k][t] * Bmat[k][u]
// X[2c][t] = z[b][c][t], X[2c+1][t] = -0.5*z^2. 64x64 tile, 4x4 microtile.
__global__ __launch_bounds__(256) void vits_gemm(
    const float* __restrict__ z, const float* __restrict__ Bmat,
    const float* __restrict__ avec, float* __restrict__ out)
{
    const int b  = blockIdx.z;
    const int t0 = blockIdx.y * 64;
    const int u0 = blockIdx.x * 64;
    __shared__ float As[16][68];
    __shared__ float Bs[16][68];
    const int tid = threadIdx.x;
    const int tx = tid & 15, ty = tid >> 4;
    float acc[4][4] = {};
    const float* zb = z    + (size_t)b * CC * TS;
    const float* Bb = Bmat + (size_t)b * KK * TT;
    for (int kc = 0; kc < KK/16; ++kc) {
        {
            int c_l = tid >> 5;            // 0..7
            int t_l = (tid & 31) * 2;
            const float* zp = zb + (size_t)(kc*8 + c_l)*TS + t0 + t_l;
            float2 zv = *(const float2*)zp;
            float2 z1 = make_float2(zv.x, zv.y);
            float2 z2 = make_float2(-0.5f*zv.x*zv.x, -0.5f*zv.y*zv.y);
            *(float2*)&As[2*c_l  ][t_l] = z1;
            *(float2*)&As[2*c_l+1][t_l] = z2;
            int k_l = tid >> 4;            // 0..15
            int u_l = (tid & 15) * 4;
            const float* bp = Bb + (size_t)(kc*16 + k_l)*TT + u0 + u_l;
            *(float4*)&Bs[k_l][u_l] = *(const float4*)bp;
        }
        __syncthreads();
        #pragma unroll
        for (int kk = 0; kk < 16; ++kk) {
            float4 av = *(const float4*)&As[kk][ty*4];
            float4 bv = *(const float4*)&Bs[kk][tx*4];
            float aa[4] = {av.x, av.y, av.z, av.w};
            float bb[4] = {bv.x, bv.y, bv.z, bv.w};
            #pragma unroll
            for (int i = 0; i < 4; ++i)
                #pragma unroll
                for (int jj = 0; jj < 4; ++jj)
                    acc[i][jj] += aa[i]*bb[jj];
        }
        __syncthreads();
    }
    float4 a4 = *(const float4*)(avec + b*TT + u0 + tx*4);
    float ab[4] = {a4.x, a4.y, a4.z, a4.w};
    #pragma unroll
    for (int i = 0; i < 4; ++i) {
        float4 o;
        o.x = acc[i][0] + ab[0];
        o.y = acc[i][1] + ab[1];
        o.z = acc[i][2] + ab[2];
        o.w = acc[i][3] + ab[3];
        *(float4*)(out + ((size_t)b*TS + t0 + ty*4 + i)*TT + u0 + tx*4) = o;
    }
}

// ---------------------------------------------------------------------------
// dp: forward Viterbi (f64) with ghost-zone wave tiling.
// 8 waves, thread tid owns auth column j=tid and ghost column j-64 (copy of
// left neighbor wave's region). Influence moves <=1 column per step, so the
// ghost copy stays valid for 63 steps; refresh every 32 via one LDS exchange.
// dirs bit-packed per j along t (32-t windows), bank-swizzled.
#define DIRS(j,w) dirs[((j)<<6) | ((w) ^ ((j) & 31))]

__global__ __launch_bounds__(512, 1) void vits_dp(
    const float* __restrict__ nc,
    const int* __restrict__ spec_len, const int* __restrict__ text_len,
    float* __restrict__ dur, float* __restrict__ logw, int* __restrict__ jt)
{
    __shared__ unsigned int dirs[TT*(TS/32)];   // 512*64 u32 = 128 KB (swizzled)
    __shared__ double qrow[TT];                 // 4 KB
    __shared__ int Tr[TT + 1];                  // 2 KB

    const int tid  = threadIdx.x;
    const int lane = tid & 63;
    const int wid  = tid >> 6;
    const int b = blockIdx.x;
    const int SL = spec_len[b], TL = text_len[b];
    const bool w0 = (wid == 0);
    const int rotl = (lane + 63) & 63;          // rotate-by-1 source lane

    double qa = (tid == 0)  ? 0.0 : NEGC;       // auth col j=tid, value q[t-1]
    double qg = (tid == 64) ? 0.0 : NEGC;       // ghost col j=tid-64
    unsigned int bits = 0;

    const float* nca = nc + (size_t)b*TS*TT + tid;
    const float* ncg = nca - (w0 ? 0 : 64);     // clamp so wave0 doesn't underflow

    // depth-4 register prefetch ring (static indices via full unroll)
    float pfA[4], pfG[4];
    #pragma unroll
    for (int i = 0; i < 4; ++i) {
        int tp = (i < SL) ? i : (SL - 1);
        pfA[i] = nca[(size_t)tp*TT];
        pfG[i] = ncg[(size_t)tp*TT];
    }

    int tb = 0;
    for (; tb + 32 <= SL; tb += 32) {
        #pragma unroll
        for (int s = 0; s < 32; ++s) {
            const int t = tb + s;
            float fa = pfA[s & 3], fg = pfG[s & 3];
            int tp = t + 4; if (tp > SL - 1) tp = SL - 1;
            pfA[s & 3] = nca[(size_t)tp*TT];
            pfG[s & 3] = ncg[(size_t)tp*TT];

            double rotg = __shfl(qg, rotl);       // lane L gets qg[L-1]; lane0 gets qg[63]
            double upa  = __shfl_up(qa, 1);
            double qprev = (lane == 0) ? rotg : upa;   // q[t-1][j-1]
            bool d = (qprev >= qa);                    // ref: q_shift >= q
            bits = (bits << 1) | (unsigned)d;
            qa = (double)fa + (d ? qprev : qa);
            bool dg = (rotg >= qg);
            double qgn = (double)fg + (dg ? rotg : qg);
            qg = w0 ? NEGC : qgn;

            if (s == 31) {
                int w = t >> 5;
                DIRS(tid, w) = bits; bits = 0;
                qrow[tid] = qa;
                __syncthreads();
                if (!w0) qg = qrow[tid - 64];
                __syncthreads();
            }
        }
    }
    // tail (SL & 31 steps) — longest block (SL=2048) has no tail
    for (int t = tb; t < SL; ++t) {
        float fa = nca[(size_t)t*TT];
        float fg = ncg[(size_t)t*TT];
        double rotg = __shfl(qg, rotl);
        double upa  = __shfl_up(qa, 1);
        double qprev = (lane == 0) ? rotg : upa;
        bool d = (qprev >= qa);
        bits = (bits << 1) | (unsigned)d;
        qa = (double)fa + (d ? qprev : qa);
        bool dg = (rotg >= qg);
        double qgn = (double)fg + (dg ? rotg : qg);
        qg = w0 ? NEGC : qgn;
    }
    if (SL & 31) {
        int w = SL >> 5, r = SL & 31;
        DIRS(tid, w) = bits << (32 - r);
    }
    __syncthreads();

    for (int i = tid; i <= TT; i += 512) Tr[i] = 0;
    __syncthreads();

    if (tid == 0) {
        Tr[TL] = SL;
        int j = TL - 1, tc = SL - 1;
        // Tr[j] = first frame aligned to text index j (transition time)
        while (j > 0 && tc >= 0) {
            int w = tc >> 5;
            int bcur = 31 - (tc & 31);
            unsigned int W = DIRS(j, w) & (0xFFFFFFFFu << bcur);
            if (W) {
                int bp = __ffs(W) - 1;          // lowest set bit >= bcur
                int tp = (w << 5) + 31 - bp;    // = largest t' <= tc with d=1
                Tr[j] = tp;
                --j;
                tc = tp - 1;
            } else {
                if (w == 0) break;
                tc = (w << 5) - 1;
            }
        }
    }
    __syncthreads();

    for (int u = tid; u < TT; u += 512) {
        float dv = (u < TL) ? (float)(Tr[u+1] - Tr[u]) : 0.0f;
        dur[b*TT + u] = dv;
        logw[b*TT + u] = (u < TL) ? logf(dv + 1e-6f) : 0.0f;
    }
    // jt: range-fill [Tr[u], Tr[u+1]) -> u
    for (int u = 0; u < TL; ++u) {
        int t1 = Tr[u+1];
        for (int t = Tr[u] + tid; t < t1; t += 512) jt[b*TS + t] = u;
    }
    for (int t = SL + tid; t < TS; t += 512) jt[b*TS + t] = -1;
}

// ---------------------------------------------------------------------------
// path: path[b][t][u] = (u == jt[b][t]) ? 1 : 0   (float4-vectorized)
__global__ void vits_path(const int* __restrict__ jt, float4* __restrict__ path)
{
    int idx = blockIdx.x*blockDim.x + threadIdx.x;
    const int total = BB*TS*(TT/4);
    for (; idx < total; idx += gridDim.x*blockDim.x) {
        int u4 = idx & (TT/4 - 1);
        int bt = idx >> 7;
        int j = jt[bt];
        float4 v = make_float4(0.f,0.f,0.f,0.f);
        int r = j - (u4 << 2);
        if (r >= 0 && r < 4) ((float*)&v)[r] = 1.f;
        path[idx] = v;
    }
}

// ---------------------------------------------------------------------------
// m/logs expansion: out[b][c][t] = (jt>=0) ? src[b][c][jt] : 0
__global__ void vits_mlexp(const int* __restrict__ jt,
    const float* __restrict__ m_p, const float* __restrict__ logs_p,
    float4* __restrict__ mexp, float4* __restrict__ lexp)
{
    int idx = blockIdx.x*blockDim.x + threadIdx.x;
    const int total = BB*CC*(TS/4);
    for (; idx < total; idx += gridDim.x*blockDim.x) {
        int t4 = idx & (TS/4 - 1);
        int bc = idx >> 9;
        int b = bc / CC;
        int4 jv = *(const int4*)(jt + b*TS + (t4 << 2));
        const float* mrow = m_p    + (size_t)bc*TT;
        const float* lrow = logs_p + (size_t)bc*TT;
        float4 mv, lv;
        mv.x = (jv.x >= 0) ? mrow[jv.x] : 0.f;  lv.x = (jv.x >= 0) ? lrow[jv.x] : 0.f;
        mv.y = (jv.y >= 0) ? mrow[jv.y] : 0.f;  lv.y = (jv.y >= 0) ? lrow[jv.y] : 0.f;
        mv.z = (jv.z >= 0) ? mrow[jv.z] : 0.f;  lv.z = (jv.z >= 0) ? lrow[jv.z] : 0.f;
        mv.w = (jv.w >= 0) ? mrow[jv.w] : 0.f;  lv.w = (jv.w >= 0) ? lrow[jv.w] : 0.f;
        mexp[idx] = mv;
        lexp[idx] = lv;
    }
}

// ---------------------------------------------------------------------------
extern "C" void kernel_launch(void* const* d_in, const int* in_sizes, int n_in,
                              void* d_out, int out_size, void* d_ws, size_t ws_size,
                              hipStream_t stream) {
    const float* z_p      = (const float*)d_in[0];
    const float* m_p      = (const float*)d_in[1];
    const float* logs_p   = (const float*)d_in[2];
    const int*   spec_len = (const int*)d_in[3];
    const int*   text_len = (const int*)d_in[4];
    float* out = (float*)d_out;

    float* Bmat = (float*)d_ws;                  // [B][384][512] f32 = 12.6 MB
    float* avec = Bmat + (size_t)BB*KK*TT;       // [B][512]
    int*   jt   = (int*)(avec + BB*TT);          // [B][2048]

    float* path  = out + OFF_PATH;   // doubles as neg_cent staging
    float* dur   = out + OFF_DUR;
    float* logw  = out + OFF_LOGW;
    float* mexp  = out + OFF_MEXP;
    float* lexp  = out + OFF_LEXP;
    float* tmask = out + OFF_TMASK;
    float* smask = out + OFF_SMASK;

    vits_prep<<<BB, 512, 0, stream>>>(m_p, logs_p, spec_len, text_len,
                                      Bmat, avec, tmask, smask);
    vits_gemm<<<dim3(TT/64, TS/64, BB), 256, 0, stream>>>(z_p, Bmat, avec, path);
    vits_dp<<<BB, 512, 0, stream>>>(path, spec_len, text_len, dur, logw, jt);
    vits_path<<<2048, 256, 0, stream>>>(jt, (float4*)path);
    vits_mlexp<<<2048, 256, 0, stream>>>(jt, m_p, logs_p, (float4*)mexp, (float4*)lexp);
}

// Round 5
// 544.021 us; speedup vs baseline: 1.2139x; 1.0272x over previous
//
#include <hip/hip_runtime.h>
#include <hip/hip_bf16.h>
#include <math.h>

// Problem constants (fixed by setup_inputs)
#define BB 16
#define CC 192
#define TS 2048
#define TT 512
#define KK 384   // 2*CC

// d_out float offsets
#define OFF_PATH 0
#define OFF_DUR  (16777216)
#define OFF_LOGW (OFF_DUR + 8192)
#define OFF_MEXP (OFF_LOGW + 8192)
#define OFF_LEXP (OFF_MEXP + 6291456)
#define OFF_TMASK (OFF_LEXP + 6291456)
#define OFF_SMASK (OFF_TMASK + 8192)

#define NEGC (-1e9)

// ---------------------------------------------------------------------------
// prep: per (b,u): s = exp(-2 logs), Bmat rows {m*s, s}, avec = nc1+nc4,
// plus text_mask / spec_mask outputs.
__global__ __launch_bounds__(512) void vits_prep(
    const float* __restrict__ m_p, const float* __restrict__ logs_p,
    const int* __restrict__ spec_len, const int* __restrict__ text_len,
    float* __restrict__ Bmat, float* __restrict__ avec,
    float* __restrict__ tmask, float* __restrict__ smask)
{
    const int b = blockIdx.x;
    const int u = threadIdx.x;
    const float C0 = -0.91893853320467274178f; // -0.5*log(2*pi)
    float a_acc = 0.f;
    for (int c = 0; c < CC; ++c) {
        float lg = logs_p[((size_t)b*CC + c)*TT + u];
        float mm = m_p[((size_t)b*CC + c)*TT + u];
        float s  = expf(-2.f*lg);
        float ms = mm * s;
        Bmat[((size_t)b*KK + 2*c    )*TT + u] = ms;  // pairs with z      -> neg_cent3
        Bmat[((size_t)b*KK + 2*c + 1)*TT + u] = s;   // pairs with -.5z^2 -> neg_cent2
        a_acc += C0 - lg - 0.5f*mm*ms;               // nc1 + nc4 terms
    }
    avec[b*TT + u] = a_acc;
    tmask[b*TT + u] = (u < text_len[b]) ? 1.f : 0.f;
    for (int t = u; t < TS; t += TT)
        smask[b*TS + t] = (t < spec_len[b]) ? 1.f : 0.f;
}

// ---------------------------------------------------------------------------
// gemm: nc[b][t][u] = avec[b][u] + sum_k X[k][t] * Bmat[k][u]
// X[2c][t] = z[b][c][t], X[2c+1][t] = -0.5*z^2. 64x64 tile, 4x4 microtile.
__global__ __launch_bounds__(256) void vits_gemm(
    const float* __restrict__ z, const float* __restrict__ Bmat,
    const float* __restrict__ avec, float* __restrict__ out)
{
    const int b  = blockIdx.z;
    const int t0 = blockIdx.y * 64;
    const int u0 = blockIdx.x * 64;
    __shared__ float As[16][68];
    __shared__ float Bs[16][68];
    const int tid = threadIdx.x;
    const int tx = tid & 15, ty = tid >> 4;
    float acc[4][4] = {};
    const float* zb = z    + (size_t)b * CC * TS;
    const float* Bb = Bmat + (size_t)b * KK * TT;
    for (int kc = 0; kc < KK/16; ++kc) {
        {
            int c_l = tid >> 5;            // 0..7
            int t_l = (tid & 31) * 2;
            const float* zp = zb + (size_t)(kc*8 + c_l)*TS + t0 + t_l;
            float2 zv = *(const float2*)zp;
            float2 z1 = make_float2(zv.x, zv.y);
            float2 z2 = make_float2(-0.5f*zv.x*zv.x, -0.5f*zv.y*zv.y);
            *(float2*)&As[2*c_l  ][t_l] = z1;
            *(float2*)&As[2*c_l+1][t_l] = z2;
            int k_l = tid >> 4;            // 0..15
            int u_l = (tid & 15) * 4;
            const float* bp = Bb + (size_t)(kc*16 + k_l)*TT + u0 + u_l;
            *(float4*)&Bs[k_l][u_l] = *(const float4*)bp;
        }
        __syncthreads();
        #pragma unroll
        for (int kk = 0; kk < 16; ++kk) {
            float4 av = *(const float4*)&As[kk][ty*4];
            float4 bv = *(const float4*)&Bs[kk][tx*4];
            float aa[4] = {av.x, av.y, av.z, av.w};
            float bb[4] = {bv.x, bv.y, bv.z, bv.w};
            #pragma unroll
            for (int i = 0; i < 4; ++i)
                #pragma unroll
                for (int jj = 0; jj < 4; ++jj)
                    acc[i][jj] += aa[i]*bb[jj];
        }
        __syncthreads();
    }
    float4 a4 = *(const float4*)(avec + b*TT + u0 + tx*4);
    float ab[4] = {a4.x, a4.y, a4.z, a4.w};
    #pragma unroll
    for (int i = 0; i < 4; ++i) {
        float4 o;
        o.x = acc[i][0] + ab[0];
        o.y = acc[i][1] + ab[1];
        o.z = acc[i][2] + ab[2];
        o.w = acc[i][3] + ab[3];
        *(float4*)(out + ((size_t)b*TS + t0 + ty*4 + i)*TT + u0 + tx*4) = o;
    }
}

// ---------------------------------------------------------------------------
// DPP wave-wide lane shifts (gfx9-lineage keeps wave_shr/wave_ror DPP ctrls).
// shr1: lane n <- lane n-1, lane 0 keeps old (bound_ctrl=0, old=own value).
// ror1: lane n <- lane (n-1)&63 (lane 0 <- lane 63).
__device__ __forceinline__ double dpp_shr1(double x) {
    union { double d; int i[2]; } u, r;
    u.d = x;
    r.i[0] = __builtin_amdgcn_update_dpp(u.i[0], u.i[0], 0x138, 0xF, 0xF, false);
    r.i[1] = __builtin_amdgcn_update_dpp(u.i[1], u.i[1], 0x138, 0xF, 0xF, false);
    return r.d;
}
__device__ __forceinline__ double dpp_ror1(double x) {
    union { double d; int i[2]; } u, r;
    u.d = x;
    r.i[0] = __builtin_amdgcn_update_dpp(0, u.i[0], 0x13C, 0xF, 0xF, false);
    r.i[1] = __builtin_amdgcn_update_dpp(0, u.i[1], 0x13C, 0xF, 0xF, false);
    return r.d;
}

// ---------------------------------------------------------------------------
// dp: forward Viterbi (f64) with ghost-zone wave tiling.
// 8 waves, thread tid owns auth column j=tid and ghost column j-64 (copy of
// left neighbor wave's region). Influence moves <=1 column per step, so the
// ghost copy stays valid for 63 steps; refresh every 32 via one LDS exchange.
// Cross-lane shifts via DPP (VALU, ~2cyc) instead of ds_bpermute (~120cyc).
// dirs bit-packed per j along t (32-t windows), bank-swizzled.
#define DIRS(j,w) dirs[((j)<<6) | ((w) ^ ((j) & 31))]

__global__ __launch_bounds__(512, 1) void vits_dp(
    const float* __restrict__ nc,
    const int* __restrict__ spec_len, const int* __restrict__ text_len,
    float* __restrict__ dur, float* __restrict__ logw, int* __restrict__ jt)
{
    __shared__ unsigned int dirs[TT*(TS/32)];   // 512*64 u32 = 128 KB (swizzled)
    __shared__ double qrow[TT];                 // 4 KB
    __shared__ int Tr[TT + 1];                  // 2 KB

    const int tid  = threadIdx.x;
    const int lane = tid & 63;
    const int wid  = tid >> 6;
    const int b = blockIdx.x;
    const int SL = spec_len[b], TL = text_len[b];
    const bool w0 = (wid == 0);
    const bool l0 = (lane == 0);

    double qa = (tid == 0)  ? 0.0 : NEGC;       // auth col j=tid, value q[t-1]
    double qg = (tid == 64) ? 0.0 : NEGC;       // ghost col j=tid-64
    unsigned int bits = 0;

    const float* nca = nc + (size_t)b*TS*TT + tid;
    const float* ncg = nca - (w0 ? 0 : 64);     // clamp so wave0 doesn't underflow

    // depth-4 register prefetch ring (static indices via full unroll)
    float pfA[4], pfG[4];
    #pragma unroll
    for (int i = 0; i < 4; ++i) {
        int tp = (i < SL) ? i : (SL - 1);
        pfA[i] = nca[(size_t)tp*TT];
        pfG[i] = ncg[(size_t)tp*TT];
    }

    int tb = 0;
    for (; tb + 32 <= SL; tb += 32) {
        #pragma unroll
        for (int s = 0; s < 32; ++s) {
            const int t = tb + s;
            float fa = pfA[s & 3], fg = pfG[s & 3];
            int tp = t + 4; if (tp > SL - 1) tp = SL - 1;
            pfA[s & 3] = nca[(size_t)tp*TT];
            pfG[s & 3] = ncg[(size_t)tp*TT];

            double rotg = dpp_ror1(qg);           // lane L gets qg[L-1]; lane0 gets qg[63]
            double upa  = dpp_shr1(qa);           // lane L gets qa[L-1]; lane0 keeps own
            double qprev = l0 ? rotg : upa;       // q[t-1][j-1]
            bool d = (qprev >= qa);               // ref: q_shift >= q
            bits = (bits << 1) | (unsigned)d;
            qa = (double)fa + (d ? qprev : qa);
            bool dg = (rotg >= qg);
            double qgn = (double)fg + (dg ? rotg : qg);
            qg = w0 ? NEGC : qgn;

            if (s == 31) {
                int w = t >> 5;
                DIRS(tid, w) = bits; bits = 0;
                qrow[tid] = qa;
                __syncthreads();
                if (!w0) qg = qrow[tid - 64];
                __syncthreads();
            }
        }
    }
    // tail (SL & 31 steps) — longest block (SL=2048) has no tail
    for (int t = tb; t < SL; ++t) {
        float fa = nca[(size_t)t*TT];
        float fg = ncg[(size_t)t*TT];
        double rotg = dpp_ror1(qg);
        double upa  = dpp_shr1(qa);
        double qprev = l0 ? rotg : upa;
        bool d = (qprev >= qa);
        bits = (bits << 1) | (unsigned)d;
        qa = (double)fa + (d ? qprev : qa);
        bool dg = (rotg >= qg);
        double qgn = (double)fg + (dg ? rotg : qg);
        qg = w0 ? NEGC : qgn;
    }
    if (SL & 31) {
        int w = SL >> 5, r = SL & 31;
        DIRS(tid, w) = bits << (32 - r);
    }
    __syncthreads();

    for (int i = tid; i <= TT; i += 512) Tr[i] = 0;
    __syncthreads();

    if (tid == 0) {
        Tr[TL] = SL;
        int j = TL - 1, tc = SL - 1;
        // Tr[j] = first frame aligned to text index j (transition time)
        while (j > 0 && tc >= 0) {
            int w = tc >> 5;
            int bcur = 31 - (tc & 31);
            unsigned int W = DIRS(j, w) & (0xFFFFFFFFu << bcur);
            if (W) {
                int bp = __ffs(W) - 1;          // lowest set bit >= bcur
                int tp = (w << 5) + 31 - bp;    // = largest t' <= tc with d=1
                Tr[j] = tp;
                --j;
                tc = tp - 1;
            } else {
                if (w == 0) break;
                tc = (w << 5) - 1;
            }
        }
    }
    __syncthreads();

    for (int u = tid; u < TT; u += 512) {
        float dv = (u < TL) ? (float)(Tr[u+1] - Tr[u]) : 0.0f;
        dur[b*TT + u] = dv;
        logw[b*TT + u] = (u < TL) ? logf(dv + 1e-6f) : 0.0f;
    }
    // jt: range-fill [Tr[u], Tr[u+1]) -> u
    for (int u = 0; u < TL; ++u) {
        int t1 = Tr[u+1];
        for (int t = Tr[u] + tid; t < t1; t += 512) jt[b*TS + t] = u;
    }
    for (int t = SL + tid; t < TS; t += 512) jt[b*TS + t] = -1;
}

// ---------------------------------------------------------------------------
// path: path[b][t][u] = (u == jt[b][t]) ? 1 : 0   (float4-vectorized)
__global__ void vits_path(const int* __restrict__ jt, float4* __restrict__ path)
{
    int idx = blockIdx.x*blockDim.x + threadIdx.x;
    const int total = BB*TS*(TT/4);
    for (; idx < total; idx += gridDim.x*blockDim.x) {
        int u4 = idx & (TT/4 - 1);
        int bt = idx >> 7;
        int j = jt[bt];
        float4 v = make_float4(0.f,0.f,0.f,0.f);
        int r = j - (u4 << 2);
        if (r >= 0 && r < 4) ((float*)&v)[r] = 1.f;
        path[idx] = v;
    }
}

// ---------------------------------------------------------------------------
// m/logs expansion: out[b][c][t] = (jt>=0) ? src[b][c][jt] : 0
__global__ void vits_mlexp(const int* __restrict__ jt,
    const float* __restrict__ m_p, const float* __restrict__ logs_p,
    float4* __restrict__ mexp, float4* __restrict__ lexp)
{
    int idx = blockIdx.x*blockDim.x + threadIdx.x;
    const int total = BB*CC*(TS/4);
    for (; idx < total; idx += gridDim.x*blockDim.x) {
        int t4 = idx & (TS/4 - 1);
        int bc = idx >> 9;
        int b = bc / CC;
        int4 jv = *(const int4*)(jt + b*TS + (t4 << 2));
        const float* mrow = m_p    + (size_t)bc*TT;
        const float* lrow = logs_p + (size_t)bc*TT;
        float4 mv, lv;
        mv.x = (jv.x >= 0) ? mrow[jv.x] : 0.f;  lv.x = (jv.x >= 0) ? lrow[jv.x] : 0.f;
        mv.y = (jv.y >= 0) ? mrow[jv.y] : 0.f;  lv.y = (jv.y >= 0) ? lrow[jv.y] : 0.f;
        mv.z = (jv.z >= 0) ? mrow[jv.z] : 0.f;  lv.z = (jv.z >= 0) ? lrow[jv.z] : 0.f;
        mv.w = (jv.w >= 0) ? mrow[jv.w] : 0.f;  lv.w = (jv.w >= 0) ? lrow[jv.w] : 0.f;
        mexp[idx] = mv;
        lexp[idx] = lv;
    }
}

// ---------------------------------------------------------------------------
extern "C" void kernel_launch(void* const* d_in, const int* in_sizes, int n_in,
                              void* d_out, int out_size, void* d_ws, size_t ws_size,
                              hipStream_t stream) {
    const float* z_p      = (const float*)d_in[0];
    const float* m_p      = (const float*)d_in[1];
    const float* logs_p   = (const float*)d_in[2];
    const int*   spec_len = (const int*)d_in[3];
    const int*   text_len = (const int*)d_in[4];
    float* out = (float*)d_out;

    float* Bmat = (float*)d_ws;                  // [B][384][512] f32 = 12.6 MB
    float* avec = Bmat + (size_t)BB*KK*TT;       // [B][512]
    int*   jt   = (int*)(avec + BB*TT);          // [B][2048]

    float* path  = out + OFF_PATH;   // doubles as neg_cent staging
    float* dur   = out + OFF_DUR;
    float* logw  = out + OFF_LOGW;
    float* mexp  = out + OFF_MEXP;
    float* lexp  = out + OFF_LEXP;
    float* tmask = out + OFF_TMASK;
    float* smask = out + OFF_SMASK;

    vits_prep<<<BB, 512, 0, stream>>>(m_p, logs_p, spec_len, text_len,
                                      Bmat, avec, tmask, smask);
    vits_gemm<<<dim3(TT/64, TS/64, BB), 256, 0, stream>>>(z_p, Bmat, avec, path);
    vits_dp<<<BB, 512, 0, stream>>>(path, spec_len, text_len, dur, logw, jt);
    vits_path<<<2048, 256, 0, stream>>>(jt, (float4*)path);
    vits_mlexp<<<2048, 256, 0, stream>>>(jt, m_p, logs_p, (float4*)mexp, (float4*)lexp);
}

// Round 6
// 482.390 us; speedup vs baseline: 1.3690x; 1.1278x over previous
//
#include <hip/hip_runtime.h>
#include <hip/hip_bf16.h>
#include <math.h>

// Problem constants (fixed by setup_inputs)
#define BB 16
#define CC 192
#define TS 2048
#define TT 512
#define KK 384   // 2*CC

// d_out float offsets
#define OFF_PATH 0
#define OFF_DUR  (16777216)
#define OFF_LOGW (OFF_DUR + 8192)
#define OFF_MEXP (OFF_LOGW + 8192)
#define OFF_LEXP (OFF_MEXP + 6291456)
#define OFF_TMASK (OFF_LEXP + 6291456)
#define OFF_SMASK (OFF_TMASK + 8192)

#define NEGC  (-1e9)
#define NEGCF (-1e9f)

// ---------------------------------------------------------------------------
// prep: per (b,u): s = exp(-2 logs), Bmat rows {m*s, s}, avec = nc1+nc4,
// plus text_mask / spec_mask outputs.
__global__ __launch_bounds__(512) void vits_prep(
    const float* __restrict__ m_p, const float* __restrict__ logs_p,
    const int* __restrict__ spec_len, const int* __restrict__ text_len,
    float* __restrict__ Bmat, float* __restrict__ avec,
    float* __restrict__ tmask, float* __restrict__ smask)
{
    const int b = blockIdx.x;
    const int u = threadIdx.x;
    const float C0 = -0.91893853320467274178f; // -0.5*log(2*pi)
    float a_acc = 0.f;
    for (int c = 0; c < CC; ++c) {
        float lg = logs_p[((size_t)b*CC + c)*TT + u];
        float mm = m_p[((size_t)b*CC + c)*TT + u];
        float s  = expf(-2.f*lg);
        float ms = mm * s;
        Bmat[((size_t)b*KK + 2*c    )*TT + u] = ms;  // pairs with z      -> neg_cent3
        Bmat[((size_t)b*KK + 2*c + 1)*TT + u] = s;   // pairs with -.5z^2 -> neg_cent2
        a_acc += C0 - lg - 0.5f*mm*ms;               // nc1 + nc4 terms
    }
    avec[b*TT + u] = a_acc;
    tmask[b*TT + u] = (u < text_len[b]) ? 1.f : 0.f;
    for (int t = u; t < TS; t += TT)
        smask[b*TS + t] = (t < spec_len[b]) ? 1.f : 0.f;
}

// ---------------------------------------------------------------------------
// gemm: nc[b][t][u] = avec[b][u] + sum_k X[k][t] * Bmat[k][u]
// X[2c][t] = z[b][c][t], X[2c+1][t] = -0.5*z^2. 64x64 tile, 4x4 microtile.
__global__ __launch_bounds__(256) void vits_gemm(
    const float* __restrict__ z, const float* __restrict__ Bmat,
    const float* __restrict__ avec, float* __restrict__ out)
{
    const int b  = blockIdx.z;
    const int t0 = blockIdx.y * 64;
    const int u0 = blockIdx.x * 64;
    __shared__ float As[16][68];
    __shared__ float Bs[16][68];
    const int tid = threadIdx.x;
    const int tx = tid & 15, ty = tid >> 4;
    float acc[4][4] = {};
    const float* zb = z    + (size_t)b * CC * TS;
    const float* Bb = Bmat + (size_t)b * KK * TT;
    for (int kc = 0; kc < KK/16; ++kc) {
        {
            int c_l = tid >> 5;            // 0..7
            int t_l = (tid & 31) * 2;
            const float* zp = zb + (size_t)(kc*8 + c_l)*TS + t0 + t_l;
            float2 zv = *(const float2*)zp;
            float2 z1 = make_float2(zv.x, zv.y);
            float2 z2 = make_float2(-0.5f*zv.x*zv.x, -0.5f*zv.y*zv.y);
            *(float2*)&As[2*c_l  ][t_l] = z1;
            *(float2*)&As[2*c_l+1][t_l] = z2;
            int k_l = tid >> 4;            // 0..15
            int u_l = (tid & 15) * 4;
            const float* bp = Bb + (size_t)(kc*16 + k_l)*TT + u0 + u_l;
            *(float4*)&Bs[k_l][u_l] = *(const float4*)bp;
        }
        __syncthreads();
        #pragma unroll
        for (int kk = 0; kk < 16; ++kk) {
            float4 av = *(const float4*)&As[kk][ty*4];
            float4 bv = *(const float4*)&Bs[kk][tx*4];
            float aa[4] = {av.x, av.y, av.z, av.w};
            float bb[4] = {bv.x, bv.y, bv.z, bv.w};
            #pragma unroll
            for (int i = 0; i < 4; ++i)
                #pragma unroll
                for (int jj = 0; jj < 4; ++jj)
                    acc[i][jj] += aa[i]*bb[jj];
        }
        __syncthreads();
    }
    float4 a4 = *(const float4*)(avec + b*TT + u0 + tx*4);
    float ab[4] = {a4.x, a4.y, a4.z, a4.w};
    #pragma unroll
    for (int i = 0; i < 4; ++i) {
        float4 o;
        o.x = acc[i][0] + ab[0];
        o.y = acc[i][1] + ab[1];
        o.z = acc[i][2] + ab[2];
        o.w = acc[i][3] + ab[3];
        *(float4*)(out + ((size_t)b*TS + t0 + ty*4 + i)*TT + u0 + tx*4) = o;
    }
}

// ---------------------------------------------------------------------------
// DPP full-wave rotate-by-1: lane n <- lane (n-1)&63 (wave_ror:1 = 0x13C).
__device__ __forceinline__ float dpp_ror1_f32(float v) {
    union { float f; int i; } u, r;
    u.f = v;
    r.i = __builtin_amdgcn_update_dpp(0, u.i, 0x13C, 0xF, 0xF, false);
    return r.f;
}

// ---------------------------------------------------------------------------
// dp: forward Viterbi (f32, same op order as the f32 reference) with
// ghost-zone wave tiling. 8 waves; thread tid owns auth column j=tid and a
// ghost copy of column tid-64 (left wave's region). Influence moves <=1
// column/step, so ghosts stay valid for 63 steps; refresh every 32 via LDS.
// Cross-lane shift via DPP wave_ror (VALU). Boundary select folded into the
// rotate input: x = (lane==63 ? qg : qa); ror1(x) gives lane l qa[l-1], and
// lane 0 gets qg[63] = col (wid*64 - 1). Wave0's qg is pinned at NEGC so
// lane0 of wave0 sees q_shift = NEG per the reference.
// dirs bit-packed per auth j along t (32-t windows), bank-swizzled.
#define DIRS(j,w) dirs[((j)<<6) | ((w) ^ ((j) & 31))]
#define RING 8

__global__ __launch_bounds__(512, 1) void vits_dp(
    const float* __restrict__ nc,
    const int* __restrict__ spec_len, const int* __restrict__ text_len,
    float* __restrict__ dur, float* __restrict__ logw, int* __restrict__ jt)
{
    __shared__ unsigned int dirs[TT*(TS/32)];   // 512*64 u32 = 128 KB (swizzled)
    __shared__ float qrow[TT];                  // 2 KB
    __shared__ int Tr[TT + 1];                  // 2 KB

    const int tid  = threadIdx.x;
    const int lane = tid & 63;
    const int wid  = tid >> 6;
    const int b = blockIdx.x;
    const int SL = spec_len[b], TL = text_len[b];
    const bool w0 = (wid == 0);
    const bool l63 = (lane == 63);

    float qa = (tid == 0)  ? 0.0f : NEGCF;      // auth col j=tid, value q[t-1]
    float qg = (tid == 64) ? 0.0f : NEGCF;      // ghost col j=tid-64
    unsigned int bits = 0;

    const float* nca = nc + (size_t)b*TS*TT + tid;
    const float* ncg = nca - (w0 ? 0 : 64);     // clamp so wave0 doesn't underflow

    // register prefetch ring, distance RING (static indices via full unroll)
    float pfA[RING], pfG[RING];
    #pragma unroll
    for (int i = 0; i < RING; ++i) {
        int tp = (i < SL) ? i : (SL - 1);
        pfA[i] = nca[(size_t)tp*TT];
        pfG[i] = ncg[(size_t)tp*TT];
    }

    int tb = 0;
    for (; tb + 32 <= SL; tb += 32) {
        #pragma unroll
        for (int s = 0; s < 32; ++s) {
            const int t = tb + s;
            float fa = pfA[s & (RING-1)], fg = pfG[s & (RING-1)];
            int tp = t + RING; if (tp > SL - 1) tp = SL - 1;
            pfA[s & (RING-1)] = nca[(size_t)tp*TT];
            pfG[s & (RING-1)] = ncg[(size_t)tp*TT];

            float x = l63 ? qg : qa;
            float qprev = dpp_ror1_f32(x);        // lane l: qa[l-1]; lane0: qg[63]
            float rotg  = dpp_ror1_f32(qg);
            bool d = (qprev >= qa);               // ref: q_shift >= q
            bits = (bits << 1) | (unsigned)d;
            qa = fa + fmaxf(qprev, qa);
            float qgn = fg + fmaxf(rotg, qg);
            qg = w0 ? NEGCF : qgn;

            if (s == 31) {
                int w = t >> 5;
                DIRS(tid, w) = bits; bits = 0;
                qrow[tid] = qa;
                __syncthreads();
                if (!w0) qg = qrow[tid - 64];
                __syncthreads();
            }
        }
    }
    // tail (SL & 31 steps)
    for (int t = tb; t < SL; ++t) {
        float fa = nca[(size_t)t*TT];
        float fg = ncg[(size_t)t*TT];
        float x = l63 ? qg : qa;
        float qprev = dpp_ror1_f32(x);
        float rotg  = dpp_ror1_f32(qg);
        bool d = (qprev >= qa);
        bits = (bits << 1) | (unsigned)d;
        qa = fa + fmaxf(qprev, qa);
        float qgn = fg + fmaxf(rotg, qg);
        qg = w0 ? NEGCF : qgn;
    }
    if (SL & 31) {
        int w = SL >> 5, r = SL & 31;
        DIRS(tid, w) = bits << (32 - r);
    }
    __syncthreads();

    for (int i = tid; i <= TT; i += 512) Tr[i] = 0;
    __syncthreads();

    if (tid == 0) {
        Tr[TL] = SL;
        int j = TL - 1, tc = SL - 1;
        // Tr[j] = first frame aligned to text index j (transition time)
        while (j > 0 && tc >= 0) {
            int w = tc >> 5;
            int bcur = 31 - (tc & 31);
            unsigned int W = DIRS(j, w) & (0xFFFFFFFFu << bcur);
            if (W) {
                int bp = __ffs(W) - 1;          // lowest set bit >= bcur
                int tp = (w << 5) + 31 - bp;    // = largest t' <= tc with d=1
                Tr[j] = tp;
                --j;
                tc = tp - 1;
            } else {
                if (w == 0) break;
                tc = (w << 5) - 1;
            }
        }
    }
    __syncthreads();

    for (int u = tid; u < TT; u += 512) {
        float dv = (u < TL) ? (float)(Tr[u+1] - Tr[u]) : 0.0f;
        dur[b*TT + u] = dv;
        logw[b*TT + u] = (u < TL) ? logf(dv + 1e-6f) : 0.0f;
    }
    // jt: range-fill [Tr[u], Tr[u+1]) -> u
    for (int u = 0; u < TL; ++u) {
        int t1 = Tr[u+1];
        for (int t = Tr[u] + tid; t < t1; t += 512) jt[b*TS + t] = u;
    }
    for (int t = SL + tid; t < TS; t += 512) jt[b*TS + t] = -1;
}

// ---------------------------------------------------------------------------
// path: path[b][t][u] = (u == jt[b][t]) ? 1 : 0   (float4-vectorized)
__global__ void vits_path(const int* __restrict__ jt, float4* __restrict__ path)
{
    int idx = blockIdx.x*blockDim.x + threadIdx.x;
    const int total = BB*TS*(TT/4);
    for (; idx < total; idx += gridDim.x*blockDim.x) {
        int u4 = idx & (TT/4 - 1);
        int bt = idx >> 7;
        int j = jt[bt];
        float4 v = make_float4(0.f,0.f,0.f,0.f);
        int r = j - (u4 << 2);
        if (r >= 0 && r < 4) ((float*)&v)[r] = 1.f;
        path[idx] = v;
    }
}

// ---------------------------------------------------------------------------
// m/logs expansion: out[b][c][t] = (jt>=0) ? src[b][c][jt] : 0
__global__ void vits_mlexp(const int* __restrict__ jt,
    const float* __restrict__ m_p, const float* __restrict__ logs_p,
    float4* __restrict__ mexp, float4* __restrict__ lexp)
{
    int idx = blockIdx.x*blockDim.x + threadIdx.x;
    const int total = BB*CC*(TS/4);
    for (; idx < total; idx += gridDim.x*blockDim.x) {
        int t4 = idx & (TS/4 - 1);
        int bc = idx >> 9;
        int b = bc / CC;
        int4 jv = *(const int4*)(jt + b*TS + (t4 << 2));
        const float* mrow = m_p    + (size_t)bc*TT;
        const float* lrow = logs_p + (size_t)bc*TT;
        float4 mv, lv;
        mv.x = (jv.x >= 0) ? mrow[jv.x] : 0.f;  lv.x = (jv.x >= 0) ? lrow[jv.x] : 0.f;
        mv.y = (jv.y >= 0) ? mrow[jv.y] : 0.f;  lv.y = (jv.y >= 0) ? lrow[jv.y] : 0.f;
        mv.z = (jv.z >= 0) ? mrow[jv.z] : 0.f;  lv.z = (jv.z >= 0) ? lrow[jv.z] : 0.f;
        mv.w = (jv.w >= 0) ? mrow[jv.w] : 0.f;  lv.w = (jv.w >= 0) ? lrow[jv.w] : 0.f;
        mexp[idx] = mv;
        lexp[idx] = lv;
    }
}

// ---------------------------------------------------------------------------
extern "C" void kernel_launch(void* const* d_in, const int* in_sizes, int n_in,
                              void* d_out, int out_size, void* d_ws, size_t ws_size,
                              hipStream_t stream) {
    const float* z_p      = (const float*)d_in[0];
    const float* m_p      = (const float*)d_in[1];
    const float* logs_p   = (const float*)d_in[2];
    const int*   spec_len = (const int*)d_in[3];
    const int*   text_len = (const int*)d_in[4];
    float* out = (float*)d_out;

    float* Bmat = (float*)d_ws;                  // [B][384][512] f32 = 12.6 MB
    float* avec = Bmat + (size_t)BB*KK*TT;       // [B][512]
    int*   jt   = (int*)(avec + BB*TT);          // [B][2048]

    float* path  = out + OFF_PATH;   // doubles as neg_cent staging
    float* dur   = out + OFF_DUR;
    float* logw  = out + OFF_LOGW;
    float* mexp  = out + OFF_MEXP;
    float* lexp  = out + OFF_LEXP;
    float* tmask = out + OFF_TMASK;
    float* smask = out + OFF_SMASK;

    vits_prep<<<BB, 512, 0, stream>>>(m_p, logs_p, spec_len, text_len,
                                      Bmat, avec, tmask, smask);
    vits_gemm<<<dim3(TT/64, TS/64, BB), 256, 0, stream>>>(z_p, Bmat, avec, path);
    vits_dp<<<BB, 512, 0, stream>>>(path, spec_len, text_len, dur, logw, jt);
    vits_path<<<2048, 256, 0, stream>>>(jt, (float4*)path);
    vits_mlexp<<<2048, 256, 0, stream>>>(jt, m_p, logs_p, (float4*)mexp, (float4*)lexp);
}

// Round 7
// 480.336 us; speedup vs baseline: 1.3749x; 1.0043x over previous
//
#include <hip/hip_runtime.h>
#include <hip/hip_bf16.h>
#include <math.h>

// Problem constants (fixed by setup_inputs)
#define BB 16
#define CC 192
#define TS 2048
#define TT 512
#define KK 384   // 2*CC

// d_out float offsets
#define OFF_PATH 0
#define OFF_DUR  (16777216)
#define OFF_LOGW (OFF_DUR + 8192)
#define OFF_MEXP (OFF_LOGW + 8192)
#define OFF_LEXP (OFF_MEXP + 6291456)
#define OFF_TMASK (OFF_LEXP + 6291456)
#define OFF_SMASK (OFF_TMASK + 8192)

#define NEGCF (-1e9f)

// ---------------------------------------------------------------------------
// prep: per (b,u): s = exp(-2 logs), Bmat rows {m*s, s}, avec = nc1+nc4,
// plus text_mask / spec_mask outputs.
__global__ __launch_bounds__(512) void vits_prep(
    const float* __restrict__ m_p, const float* __restrict__ logs_p,
    const int* __restrict__ spec_len, const int* __restrict__ text_len,
    float* __restrict__ Bmat, float* __restrict__ avec,
    float* __restrict__ tmask, float* __restrict__ smask)
{
    const int b = blockIdx.x;
    const int u = threadIdx.x;
    const float C0 = -0.91893853320467274178f; // -0.5*log(2*pi)
    float a_acc = 0.f;
    for (int c = 0; c < CC; ++c) {
        float lg = logs_p[((size_t)b*CC + c)*TT + u];
        float mm = m_p[((size_t)b*CC + c)*TT + u];
        float s  = expf(-2.f*lg);
        float ms = mm * s;
        Bmat[((size_t)b*KK + 2*c    )*TT + u] = ms;  // pairs with z      -> neg_cent3
        Bmat[((size_t)b*KK + 2*c + 1)*TT + u] = s;   // pairs with -.5z^2 -> neg_cent2
        a_acc += C0 - lg - 0.5f*mm*ms;               // nc1 + nc4 terms
    }
    avec[b*TT + u] = a_acc;
    tmask[b*TT + u] = (u < text_len[b]) ? 1.f : 0.f;
    for (int t = u; t < TS; t += TT)
        smask[b*TS + t] = (t < spec_len[b]) ? 1.f : 0.f;
}

// ---------------------------------------------------------------------------
// gemm: nc[b][t][u] = avec[b][u] + sum_k X[k][t] * Bmat[k][u]
// X[2c][t] = z[b][c][t], X[2c+1][t] = -0.5*z^2. 64x64 tile, 4x4 microtile.
__global__ __launch_bounds__(256) void vits_gemm(
    const float* __restrict__ z, const float* __restrict__ Bmat,
    const float* __restrict__ avec, float* __restrict__ out)
{
    const int b  = blockIdx.z;
    const int t0 = blockIdx.y * 64;
    const int u0 = blockIdx.x * 64;
    __shared__ float As[16][68];
    __shared__ float Bs[16][68];
    const int tid = threadIdx.x;
    const int tx = tid & 15, ty = tid >> 4;
    float acc[4][4] = {};
    const float* zb = z    + (size_t)b * CC * TS;
    const float* Bb = Bmat + (size_t)b * KK * TT;
    for (int kc = 0; kc < KK/16; ++kc) {
        {
            int c_l = tid >> 5;            // 0..7
            int t_l = (tid & 31) * 2;
            const float* zp = zb + (size_t)(kc*8 + c_l)*TS + t0 + t_l;
            float2 zv = *(const float2*)zp;
            float2 z1 = make_float2(zv.x, zv.y);
            float2 z2 = make_float2(-0.5f*zv.x*zv.x, -0.5f*zv.y*zv.y);
            *(float2*)&As[2*c_l  ][t_l] = z1;
            *(float2*)&As[2*c_l+1][t_l] = z2;
            int k_l = tid >> 4;            // 0..15
            int u_l = (tid & 15) * 4;
            const float* bp = Bb + (size_t)(kc*16 + k_l)*TT + u0 + u_l;
            *(float4*)&Bs[k_l][u_l] = *(const float4*)bp;
        }
        __syncthreads();
        #pragma unroll
        for (int kk = 0; kk < 16; ++kk) {
            float4 av = *(const float4*)&As[kk][ty*4];
            float4 bv = *(const float4*)&Bs[kk][tx*4];
            float aa[4] = {av.x, av.y, av.z, av.w};
            float bb[4] = {bv.x, bv.y, bv.z, bv.w};
            #pragma unroll
            for (int i = 0; i < 4; ++i)
                #pragma unroll
                for (int jj = 0; jj < 4; ++jj)
                    acc[i][jj] += aa[i]*bb[jj];
        }
        __syncthreads();
    }
    float4 a4 = *(const float4*)(avec + b*TT + u0 + tx*4);
    float ab[4] = {a4.x, a4.y, a4.z, a4.w};
    #pragma unroll
    for (int i = 0; i < 4; ++i) {
        float4 o;
        o.x = acc[i][0] + ab[0];
        o.y = acc[i][1] + ab[1];
        o.z = acc[i][2] + ab[2];
        o.w = acc[i][3] + ab[3];
        *(float4*)(out + ((size_t)b*TS + t0 + ty*4 + i)*TT + u0 + tx*4) = o;
    }
}

// ---------------------------------------------------------------------------
// DPP full-wave rotate-by-1: lane n <- lane (n-1)&63 (wave_ror:1 = 0x13C).
__device__ __forceinline__ float dpp_ror1_f32(float v) {
    union { float f; int i; } u, r;
    u.f = v;
    r.i = __builtin_amdgcn_update_dpp(0, u.i, 0x13C, 0xF, 0xF, false);
    return r.f;
}

// ---------------------------------------------------------------------------
// dp: forward Viterbi (f32) with 16-wave ghost-zone tiling.
// Wave w: lanes 32-63 own auth columns w*32..w*32+31; lanes 0-31 carry a
// ghost copy of the left wave's columns (w*32-32..w*32-1). col = w*32+lane-32
// for ALL lanes, so wave_ror1 gives every lane its col-1 predecessor except
// ghost lane 0 (gets junk; corruption moves 1 lane/step and reaches ghost
// lane 31 only at step 32 == the LDS refresh cadence, so auth stays pure).
// Wave 0's ghost lanes are pinned to NEG (reference j=0 boundary).
// dirs bit-packed per auth col along t (32-t windows), bank-swizzled.
#define DIRS(j,w) dirs[((j)<<6) | ((w) ^ ((j) & 31))]
#define RING 16

__global__ __launch_bounds__(1024, 1) void vits_dp(
    const float* __restrict__ nc,
    const int* __restrict__ spec_len, const int* __restrict__ text_len,
    float* __restrict__ dur, float* __restrict__ logw, int* __restrict__ jt)
{
    __shared__ unsigned int dirs[TT*(TS/32)];   // 512*64 u32 = 128 KB (swizzled)
    __shared__ float qrow[TT];                  // 2 KB
    __shared__ int Tr[TT + 1];                  // 2 KB

    const int tid  = threadIdx.x;
    const int lane = tid & 63;
    const int wid  = tid >> 6;
    const int b = blockIdx.x;
    const int SL = spec_len[b], TL = text_len[b];
    const int col = (wid << 5) + lane - 32;      // auth if lane>=32, ghost else
    const bool auth = (lane >= 32);
    const bool w0g  = (wid == 0) && (lane < 32); // pinned-NEG ghost lanes

    float q = (col == 0) ? 0.0f : NEGCF;
    unsigned int bits = 0;

    const int colL = (col < 0) ? 0 : col;
    const float* ncb = nc + (size_t)b*TS*TT + colL;

    // register prefetch ring, distance RING (static indices via full unroll)
    float pf[RING];
    #pragma unroll
    for (int i = 0; i < RING; ++i) pf[i] = ncb[(size_t)i*TT];
    const float* pcur = ncb + (size_t)RING*TT;   // next row to fetch

    int tb = 0;
    for (; tb + 32 <= SL; tb += 32) {
        #pragma unroll
        for (int s = 0; s < 32; ++s) {
            const int t = tb + s;
            float f = pf[s & (RING-1)];
            pf[s & (RING-1)] = *pcur;            // row t+RING (may read junk past SL; never consumed)
            pcur += TT;

            float qp = dpp_ror1_f32(q);          // lane l <- q[col-1] (ghost lane0: junk, tolerated)
            bool d = (qp >= q);                  // ref: q_shift >= q
            bits = (bits << 1) | (unsigned)d;
            float qn = f + fmaxf(qp, q);
            q = w0g ? NEGCF : qn;

            if (s == 31) {
                int w = t >> 5;
                if (auth) {
                    DIRS(col, w) = bits;
                    qrow[col] = q;
                }
                bits = 0;
                __syncthreads();
                if (!auth && wid != 0) q = qrow[col];   // ghost refresh
                __syncthreads();
            }
        }
    }
    // tail (SL & 31 steps) — direct loads (no dynamic pf indexing; rule #20)
    for (int t = tb; t < SL; ++t) {
        float f = ncb[(size_t)t*TT];
        float qp = dpp_ror1_f32(q);
        bool d = (qp >= q);
        bits = (bits << 1) | (unsigned)d;
        float qn = f + fmaxf(qp, q);
        q = w0g ? NEGCF : qn;
    }
    if (SL & 31) {
        int w = SL >> 5, r = SL & 31;
        if (auth) DIRS(col, w) = bits << (32 - r);
    }
    __syncthreads();

    for (int i = tid; i <= TT; i += 1024) Tr[i] = 0;
    __syncthreads();

    if (tid == 0) {
        Tr[TL] = SL;
        int j = TL - 1, tc = SL - 1;
        // Tr[j] = first frame aligned to text index j (transition time)
        while (j > 0 && tc >= 0) {
            int w = tc >> 5;
            int bcur = 31 - (tc & 31);
            unsigned int W = DIRS(j, w) & (0xFFFFFFFFu << bcur);
            if (W) {
                int bp = __ffs(W) - 1;          // lowest set bit >= bcur
                int tp = (w << 5) + 31 - bp;    // = largest t' <= tc with d=1
                Tr[j] = tp;
                --j;
                tc = tp - 1;
            } else {
                if (w == 0) break;
                tc = (w << 5) - 1;
            }
        }
    }
    __syncthreads();

    for (int u = tid; u < TT; u += 1024) {
        float dv = (u < TL) ? (float)(Tr[u+1] - Tr[u]) : 0.0f;
        dur[b*TT + u] = dv;
        logw[b*TT + u] = (u < TL) ? logf(dv + 1e-6f) : 0.0f;
    }
    // jt: range-fill [Tr[u], Tr[u+1]) -> u
    for (int u = 0; u < TL; ++u) {
        int t1 = Tr[u+1];
        for (int t = Tr[u] + tid; t < t1; t += 1024) jt[b*TS + t] = u;
    }
    for (int t = SL + tid; t < TS; t += 1024) jt[b*TS + t] = -1;
}

// ---------------------------------------------------------------------------
// path: path[b][t][u] = (u == jt[b][t]) ? 1 : 0   (float4-vectorized)
__global__ void vits_path(const int* __restrict__ jt, float4* __restrict__ path)
{
    int idx = blockIdx.x*blockDim.x + threadIdx.x;
    const int total = BB*TS*(TT/4);
    for (; idx < total; idx += gridDim.x*blockDim.x) {
        int u4 = idx & (TT/4 - 1);
        int bt = idx >> 7;
        int j = jt[bt];
        float4 v = make_float4(0.f,0.f,0.f,0.f);
        int r = j - (u4 << 2);
        if (r >= 0 && r < 4) ((float*)&v)[r] = 1.f;
        path[idx] = v;
    }
}

// ---------------------------------------------------------------------------
// m/logs expansion: out[b][c][t] = (jt>=0) ? src[b][c][jt] : 0
__global__ void vits_mlexp(const int* __restrict__ jt,
    const float* __restrict__ m_p, const float* __restrict__ logs_p,
    float4* __restrict__ mexp, float4* __restrict__ lexp)
{
    int idx = blockIdx.x*blockDim.x + threadIdx.x;
    const int total = BB*CC*(TS/4);
    for (; idx < total; idx += gridDim.x*blockDim.x) {
        int t4 = idx & (TS/4 - 1);
        int bc = idx >> 9;
        int b = bc / CC;
        int4 jv = *(const int4*)(jt + b*TS + (t4 << 2));
        const float* mrow = m_p    + (size_t)bc*TT;
        const float* lrow = logs_p + (size_t)bc*TT;
        float4 mv, lv;
        mv.x = (jv.x >= 0) ? mrow[jv.x] : 0.f;  lv.x = (jv.x >= 0) ? lrow[jv.x] : 0.f;
        mv.y = (jv.y >= 0) ? mrow[jv.y] : 0.f;  lv.y = (jv.y >= 0) ? lrow[jv.y] : 0.f;
        mv.z = (jv.z >= 0) ? mrow[jv.z] : 0.f;  lv.z = (jv.z >= 0) ? lrow[jv.z] : 0.f;
        mv.w = (jv.w >= 0) ? mrow[jv.w] : 0.f;  lv.w = (jv.w >= 0) ? lrow[jv.w] : 0.f;
        mexp[idx] = mv;
        lexp[idx] = lv;
    }
}

// ---------------------------------------------------------------------------
extern "C" void kernel_launch(void* const* d_in, const int* in_sizes, int n_in,
                              void* d_out, int out_size, void* d_ws, size_t ws_size,
                              hipStream_t stream) {
    const float* z_p      = (const float*)d_in[0];
    const float* m_p      = (const float*)d_in[1];
    const float* logs_p   = (const float*)d_in[2];
    const int*   spec_len = (const int*)d_in[3];
    const int*   text_len = (const int*)d_in[4];
    float* out = (float*)d_out;

    float* Bmat = (float*)d_ws;                  // [B][384][512] f32 = 12.6 MB
    float* avec = Bmat + (size_t)BB*KK*TT;       // [B][512]
    int*   jt   = (int*)(avec + BB*TT);          // [B][2048]

    float* path  = out + OFF_PATH;   // doubles as neg_cent staging
    float* dur   = out + OFF_DUR;
    float* logw  = out + OFF_LOGW;
    float* mexp  = out + OFF_MEXP;
    float* lexp  = out + OFF_LEXP;
    float* tmask = out + OFF_TMASK;
    float* smask = out + OFF_SMASK;

    vits_prep<<<BB, 512, 0, stream>>>(m_p, logs_p, spec_len, text_len,
                                      Bmat, avec, tmask, smask);
    vits_gemm<<<dim3(TT/64, TS/64, BB), 256, 0, stream>>>(z_p, Bmat, avec, path);
    vits_dp<<<BB, 1024, 0, stream>>>(path, spec_len, text_len, dur, logw, jt);
    vits_path<<<2048, 256, 0, stream>>>(jt, (float4*)path);
    vits_mlexp<<<2048, 256, 0, stream>>>(jt, m_p, logs_p, (float4*)mexp, (float4*)lexp);
}